// Round 1
// baseline (3647.266 us; speedup 1.0000x reference)
//
#include <hip/hip_runtime.h>
#include <math.h>

#define BATCH 8
#define NPER 2048
#define NPTS (BATCH*NPER)   // 16384
#define KNN 30

// ---------------- concat x,pos -> x0 (NPTS x 6) ----------------
__global__ void concat_kernel(const float* __restrict__ x, const float* __restrict__ pos,
                              float* __restrict__ x0) {
    int n = blockIdx.x * blockDim.x + threadIdx.x;
    if (n >= NPTS) return;
#pragma unroll
    for (int d = 0; d < 3; ++d) {
        x0[n*6 + d]     = x[n*3 + d];
        x0[n*6 + 3 + d] = pos[n*3 + d];
    }
}

// ---------------- squared norms ----------------
template<int D>
__global__ void d2_kernel(const float* __restrict__ f, int stride, float* __restrict__ d2) {
    int n = blockIdx.x * blockDim.x + threadIdx.x;
    if (n >= NPTS) return;
    const float* r = f + (size_t)n * stride;
    float s = 0.f;
#pragma unroll
    for (int d = 0; d < D; ++d) s += r[d]*r[d];
    d2[n] = s;
}

// ---------------- kNN: block per point, K=30 smallest dist (tie: lowest idx) ----------------
template<int D>
__global__ __launch_bounds__(256) void knn_kernel(const float* __restrict__ f, int stride,
                                                  const float* __restrict__ d2,
                                                  int* __restrict__ idx) {
    __shared__ float sdist[NPER];
    __shared__ float sxi[D];
    __shared__ float sredv[4];
    __shared__ int   sredi[4];
    __shared__ int   ssel[KNN];
    int n = blockIdx.x;
    int t = threadIdx.x;
    int base = (n >> 11) << 11;
    if (t < D) sxi[t] = f[(size_t)n * stride + t];
    __syncthreads();
    float d2n = d2[n];
    for (int ml = t; ml < NPER; ml += 256) {
        int m = base + ml;
        const float* fm = f + (size_t)m * stride;
        float dot = 0.f;
        if constexpr (D % 4 == 0) {
#pragma unroll
            for (int d = 0; d < D; d += 4) {
                float4 a = *reinterpret_cast<const float4*>(fm + d);
                float4 b = *reinterpret_cast<const float4*>(&sxi[d]);
                dot += a.x*b.x + a.y*b.y + a.z*b.z + a.w*b.w;
            }
        } else {
#pragma unroll
            for (int d = 0; d < D; ++d) dot += fm[d]*sxi[d];
        }
        sdist[ml] = d2n + d2[m] - 2.f*dot;
    }
    __syncthreads();
    int lane = t & 63, wid = t >> 6;
    for (int k = 0; k < KNN; ++k) {
        float v = 3.4e38f; int id = NPER;
        for (int ml = t; ml < NPER; ml += 256) {
            float dv = sdist[ml];
            if (dv < v) { v = dv; id = ml; }
        }
#pragma unroll
        for (int off = 32; off > 0; off >>= 1) {
            float ov = __shfl_down(v, off);
            int   oi = __shfl_down(id, off);
            if (ov < v || (ov == v && oi < id)) { v = ov; id = oi; }
        }
        if (lane == 0) { sredv[wid] = v; sredi[wid] = id; }
        __syncthreads();
        if (t == 0) {
            float bv = sredv[0]; int bi = sredi[0];
#pragma unroll
            for (int w = 1; w < 4; ++w)
                if (sredv[w] < bv || (sredv[w] == bv && sredi[w] < bi)) { bv = sredv[w]; bi = sredi[w]; }
            ssel[k] = bi;
            sdist[bi] = 3.4e38f;
        }
        __syncthreads();
    }
    if (t < KNN) idx[n*KNN + t] = base + ssel[t];
}

// ---------------- EdgeConv MLP + neighbor max. 4 points/block, wave per point, lane=channel ----
template<int D>
__global__ __launch_bounds__(256) void edgeconv_kernel(const float* __restrict__ fin, int in_stride,
                                const int* __restrict__ idx,
                                const float* __restrict__ wa, const float* __restrict__ ba,
                                const float* __restrict__ wb, const float* __restrict__ bb,
                                float* __restrict__ fout, int out_stride) {
    __shared__ float sxi[4][64];
    __shared__ float sxj[4][64];
    __shared__ float sh1[4][64];
    int t = threadIdx.x;
    int w = t >> 6, lane = t & 63;
    int n = blockIdx.x * 4 + w;

    // per-lane (= output channel) register weights
    float wa2[D];                    // wa[D+d][lane]  (xj part)
#pragma unroll
    for (int d = 0; d < D; ++d) wa2[d] = wa[(size_t)(D + d)*64 + lane];
    float wbc[64];                   // wb[k][lane]
#pragma unroll
    for (int k = 0; k < 64; ++k) wbc[k] = wb[(size_t)k*64 + lane];
    float bbc = bb[lane];

    if (lane < D) sxi[w][lane] = fin[(size_t)n * in_stride + lane];
    __syncthreads();

    float basec = ba[lane];
#pragma unroll
    for (int d = 0; d < D; ++d) basec += sxi[w][d] * (wa[(size_t)d*64 + lane] - wa2[d]);

    float maxv = -3.4e38f;
    for (int jj = 0; jj < KNN; ++jj) {
        int j = idx[n*KNN + jj];
        if (lane < D) sxj[w][lane] = fin[(size_t)j * in_stride + lane];
        __syncthreads();
        float h = basec;
        if constexpr (D % 4 == 0) {
#pragma unroll
            for (int d = 0; d < D; d += 4) {
                float4 x4 = *reinterpret_cast<const float4*>(&sxj[w][d]);
                h += x4.x*wa2[d] + x4.y*wa2[d+1] + x4.z*wa2[d+2] + x4.w*wa2[d+3];
            }
        } else {
#pragma unroll
            for (int d = 0; d < D; ++d) h += sxj[w][d]*wa2[d];
        }
        h = fmaxf(h, 0.f);
        sh1[w][lane] = h;
        __syncthreads();
        float h2 = bbc;
#pragma unroll
        for (int k = 0; k < 64; k += 4) {
            float4 h4 = *reinterpret_cast<const float4*>(&sh1[w][k]);
            h2 += h4.x*wbc[k] + h4.y*wbc[k+1] + h4.z*wbc[k+2] + h4.w*wbc[k+3];
        }
        maxv = fmaxf(maxv, h2);
        __syncthreads();
    }
    fout[(size_t)n * out_stride + lane] = maxv;
}

// ---------------- fused head MLP: 192 -> 1024 -> 512 -> 128, 32 rows/block ----------------
__global__ __launch_bounds__(256) void head_kernel(const float* __restrict__ feat,
                            const float* __restrict__ hw1, const float* __restrict__ hb1,
                            const float* __restrict__ hw2, const float* __restrict__ hb2,
                            const float* __restrict__ hw3, const float* __restrict__ hb3,
                            float* __restrict__ out) {
    __shared__ float smem[16384];        // 64 KB union
    float* sfeat = smem;                 // [32][192]
    float* sh1   = smem + 32*192;        // [32][64]
    int t = threadIdx.x;
    int row0 = blockIdx.x * 32;

    for (int i = t; i < 32*192; i += 256) sfeat[i] = feat[(size_t)row0*192 + i];
    __syncthreads();

    float2 acc2[32];
    {
        float2 b = *reinterpret_cast<const float2*>(&hb2[2*t]);
#pragma unroll
        for (int r = 0; r < 32; ++r) acc2[r] = b;
    }
    int col = t & 63, rg = t >> 6;

    for (int chunk = 0; chunk < 16; ++chunk) {
        int k0 = chunk * 64;
        float acc1[8];
        float b1 = hb1[k0 + col];
#pragma unroll
        for (int i = 0; i < 8; ++i) acc1[i] = b1;
        for (int k = 0; k < 192; k += 4) {
            float w0 = hw1[(size_t)(k+0)*1024 + k0 + col];
            float w1 = hw1[(size_t)(k+1)*1024 + k0 + col];
            float w2 = hw1[(size_t)(k+2)*1024 + k0 + col];
            float w3 = hw1[(size_t)(k+3)*1024 + k0 + col];
#pragma unroll
            for (int i = 0; i < 8; ++i) {
                float4 fv = *reinterpret_cast<const float4*>(&sfeat[(rg + 4*i)*192 + k]);
                acc1[i] += fv.x*w0 + fv.y*w1 + fv.z*w2 + fv.w*w3;
            }
        }
#pragma unroll
        for (int i = 0; i < 8; ++i) sh1[(rg + 4*i)*64 + col] = fmaxf(acc1[i], 0.f);
        __syncthreads();
        for (int k = 0; k < 64; k += 4) {
            float2 wv[4];
#pragma unroll
            for (int q = 0; q < 4; ++q)
                wv[q] = *reinterpret_cast<const float2*>(&hw2[(size_t)(k0 + k + q)*512 + 2*t]);
#pragma unroll
            for (int r = 0; r < 32; ++r) {
                float4 h4 = *reinterpret_cast<const float4*>(&sh1[r*64 + k]);
                acc2[r].x += h4.x*wv[0].x + h4.y*wv[1].x + h4.z*wv[2].x + h4.w*wv[3].x;
                acc2[r].y += h4.x*wv[0].y + h4.y*wv[1].y + h4.z*wv[2].y + h4.w*wv[3].y;
            }
        }
        __syncthreads();
    }

    // write relu(h2) into sh2 = smem[32][512] (overlays sfeat/sh1; all reads done)
#pragma unroll
    for (int r = 0; r < 32; ++r) {
        float2 v; v.x = fmaxf(acc2[r].x, 0.f); v.y = fmaxf(acc2[r].y, 0.f);
        *reinterpret_cast<float2*>(&smem[r*512 + 2*t]) = v;
    }
    __syncthreads();

    int c3 = t & 127, rg2 = t >> 7;
    float acc3[16];
    float b3 = hb3[c3];
#pragma unroll
    for (int i = 0; i < 16; ++i) acc3[i] = b3;
    for (int k = 0; k < 512; k += 4) {
        float w0 = hw3[(size_t)(k+0)*128 + c3];
        float w1 = hw3[(size_t)(k+1)*128 + c3];
        float w2 = hw3[(size_t)(k+2)*128 + c3];
        float w3v = hw3[(size_t)(k+3)*128 + c3];
#pragma unroll
        for (int i = 0; i < 16; ++i) {
            float4 h4 = *reinterpret_cast<const float4*>(&smem[(rg2 + 2*i)*512 + k]);
            acc3[i] += h4.x*w0 + h4.y*w1 + h4.z*w2 + h4.w*w3v;
        }
    }
#pragma unroll
    for (int i = 0; i < 16; ++i)
        out[(size_t)(row0 + rg2 + 2*i)*128 + c3] = acc3[i];
}

extern "C" void kernel_launch(void* const* d_in, const int* in_sizes, int n_in,
                              void* d_out, int out_size, void* d_ws, size_t ws_size,
                              hipStream_t stream) {
    (void)in_sizes; (void)n_in; (void)out_size; (void)ws_size;
    const float* x   = (const float*)d_in[0];
    const float* pos = (const float*)d_in[1];
    const float* w1a = (const float*)d_in[2];
    const float* b1a = (const float*)d_in[3];
    const float* w1b = (const float*)d_in[4];
    const float* b1b = (const float*)d_in[5];
    const float* w2a = (const float*)d_in[6];
    const float* b2a = (const float*)d_in[7];
    const float* w2b = (const float*)d_in[8];
    const float* b2b = (const float*)d_in[9];
    const float* w3a = (const float*)d_in[10];
    const float* b3a = (const float*)d_in[11];
    const float* w3b = (const float*)d_in[12];
    const float* b3b = (const float*)d_in[13];
    const float* hw1 = (const float*)d_in[14];
    const float* hb1 = (const float*)d_in[15];
    const float* hw2 = (const float*)d_in[16];
    const float* hb2 = (const float*)d_in[17];
    const float* hw3 = (const float*)d_in[18];
    const float* hb3 = (const float*)d_in[19];
    float* out = (float*)d_out;

    float* ws   = (float*)d_ws;
    float* x0   = ws;                     // 16384*6
    float* feat = x0 + (size_t)NPTS*6;    // 16384*192  (x1|x2|x3)
    float* d2b  = feat + (size_t)NPTS*192;
    int*   idxb = (int*)(d2b + NPTS);     // 16384*30

    concat_kernel<<<NPTS/256, 256, 0, stream>>>(x, pos, x0);

    d2_kernel<6><<<NPTS/256, 256, 0, stream>>>(x0, 6, d2b);
    knn_kernel<6><<<NPTS, 256, 0, stream>>>(x0, 6, d2b, idxb);
    edgeconv_kernel<6><<<NPTS/4, 256, 0, stream>>>(x0, 6, idxb, w1a, b1a, w1b, b1b, feat, 192);

    d2_kernel<64><<<NPTS/256, 256, 0, stream>>>(feat, 192, d2b);
    knn_kernel<64><<<NPTS, 256, 0, stream>>>(feat, 192, d2b, idxb);
    edgeconv_kernel<64><<<NPTS/4, 256, 0, stream>>>(feat, 192, idxb, w2a, b2a, w2b, b2b, feat + 64, 192);

    d2_kernel<64><<<NPTS/256, 256, 0, stream>>>(feat + 64, 192, d2b);
    knn_kernel<64><<<NPTS, 256, 0, stream>>>(feat + 64, 192, d2b, idxb);
    edgeconv_kernel<64><<<NPTS/4, 256, 0, stream>>>(feat + 64, 192, idxb, w3a, b3a, w3b, b3b, feat + 128, 192);

    head_kernel<<<NPTS/32, 256, 0, stream>>>(feat, hw1, hb1, hw2, hb2, hw3, hb3, out);
}

// Round 2
// 2829.854 us; speedup vs baseline: 1.2889x; 1.2889x over previous
//
#include <hip/hip_runtime.h>
#include <math.h>

#define BATCH 8
#define NPER 2048
#define NPTS (BATCH*NPER)   // 16384
#define KNN 30

// ---------------- concat x,pos -> x0 (NPTS x 6) ----------------
__global__ void concat_kernel(const float* __restrict__ x, const float* __restrict__ pos,
                              float* __restrict__ x0) {
    int n = blockIdx.x * blockDim.x + threadIdx.x;
    if (n >= NPTS) return;
#pragma unroll
    for (int d = 0; d < 3; ++d) {
        x0[n*6 + d]     = x[n*3 + d];
        x0[n*6 + 3 + d] = pos[n*3 + d];
    }
}

// ---------------- squared norms ----------------
template<int D>
__global__ void d2_kernel(const float* __restrict__ f, int stride, float* __restrict__ d2) {
    int n = blockIdx.x * blockDim.x + threadIdx.x;
    if (n >= NPTS) return;
    const float* r = f + (size_t)n * stride;
    float s = 0.f;
#pragma unroll
    for (int d = 0; d < D; ++d) s += r[d]*r[d];
    d2[n] = s;
}

// ---------------- kNN v2: block = 4 query points; dist shared-compute, wave-parallel
// ---------------- radix-2 selection of the 30-smallest SET (tie: lowest idx, = top_k) ----
template<int D>
__global__ __launch_bounds__(256) void knn4_kernel(const float* __restrict__ f, int stride,
                                                   const float* __restrict__ d2,
                                                   int* __restrict__ idx) {
    __shared__ float sdist[4][NPER];      // 32 KB
    __shared__ float sxi[4][(D+3)/4*4];
    __shared__ float sd2n[4];
    int t = threadIdx.x;
    int n0 = blockIdx.x * 4;
    int base = (n0 >> 11) << 11;          // batch start (4 consecutive pts same batch)

    if (t < 4*D) {
        int q = t / D, d = t - q*D;
        sxi[q][d] = f[(size_t)(n0 + q)*stride + d];
    }
    if (t < 4) sd2n[t] = d2[n0 + t];
    __syncthreads();

    // ---- phase 1: each thread computes one candidate's distance to all 4 queries ----
    for (int j = 0; j < NPER/256; ++j) {
        int ml = t + 256*j;
        int m = base + ml;
        const float* fm = f + (size_t)m*stride;
        float d2m = d2[m];
        float dot0 = 0.f, dot1 = 0.f, dot2 = 0.f, dot3 = 0.f;
        if constexpr (D % 4 == 0) {
#pragma unroll
            for (int d = 0; d < D; d += 4) {
                float4 a  = *reinterpret_cast<const float4*>(fm + d);
                float4 b0 = *reinterpret_cast<const float4*>(&sxi[0][d]);
                float4 b1 = *reinterpret_cast<const float4*>(&sxi[1][d]);
                float4 b2 = *reinterpret_cast<const float4*>(&sxi[2][d]);
                float4 b3 = *reinterpret_cast<const float4*>(&sxi[3][d]);
                dot0 += a.x*b0.x + a.y*b0.y + a.z*b0.z + a.w*b0.w;
                dot1 += a.x*b1.x + a.y*b1.y + a.z*b1.z + a.w*b1.w;
                dot2 += a.x*b2.x + a.y*b2.y + a.z*b2.z + a.w*b2.w;
                dot3 += a.x*b3.x + a.y*b3.y + a.z*b3.z + a.w*b3.w;
            }
        } else {
#pragma unroll
            for (int d = 0; d < D; ++d) {
                float a = fm[d];
                dot0 += a*sxi[0][d];
                dot1 += a*sxi[1][d];
                dot2 += a*sxi[2][d];
                dot3 += a*sxi[3][d];
            }
        }
        sdist[0][ml] = sd2n[0] + d2m - 2.f*dot0;
        sdist[1][ml] = sd2n[1] + d2m - 2.f*dot1;
        sdist[2][ml] = sd2n[2] + d2m - 2.f*dot2;
        sdist[3][ml] = sd2n[3] + d2m - 2.f*dot3;
    }
    __syncthreads();

    // ---- phase 2: wave w selects the 30 smallest for point n0+w, no barriers ----
    int w = t >> 6, lane = t & 63;
    int n = n0 + w;

    // load 32 dists/lane, transform to order-preserving uint keys
    unsigned u[NPER/64];
#pragma unroll
    for (int i = 0; i < NPER/64; ++i) {
        float dv = sdist[w][lane + 64*i];
        int b = __float_as_int(dv);
        u[i] = (unsigned)(b ^ ((b >> 31) | 0x80000000));
    }

    // bisection: T = largest x with count(u < x) < KNN  (== 30th-smallest key)
    unsigned T = 0u;
#pragma unroll
    for (int bit = 31; bit >= 0; --bit) {
        unsigned C = T | (1u << bit);
        int c = 0;
#pragma unroll
        for (int i = 0; i < NPER/64; ++i) c += (u[i] < C) ? 1 : 0;
#pragma unroll
        for (int off = 1; off < 64; off <<= 1) c += __shfl_xor(c, off);
        if (c < KNN) T = C;
    }

    // masks of strictly-less and equal
    unsigned lm = 0u, em = 0u;
#pragma unroll
    for (int i = 0; i < NPER/64; ++i) {
        lm |= (u[i] < T)  ? (1u << i) : 0u;
        em |= (u[i] == T) ? (1u << i) : 0u;
    }
    int nl = __popc(lm);
    // wave exclusive prefix over nl
    int inc = nl;
#pragma unroll
    for (int off = 1; off < 64; off <<= 1) {
        int y = __shfl_up(inc, off);
        if (lane >= off) inc += y;
    }
    int excl = inc - nl;
    int total_less = __shfl(inc, 63);

    int* op = idx + (size_t)n * KNN;
    int slot = excl;
#pragma unroll
    for (int i = 0; i < NPER/64; ++i) {
        if (lm & (1u << i)) { op[slot] = base + i*64 + lane; ++slot; }
    }

    // fill remaining with lowest-index equals (candidate idx = i*64 + lane, ascending)
    int need = KNN - total_less;
    int running = 0;
#pragma unroll
    for (int i = 0; i < NPER/64; ++i) {
        unsigned long long bal = __ballot((em >> i) & 1u);
        if (bal) {
            unsigned long long lt = bal & ((1ull << lane) - 1ull);
            int r = running + __popcll(lt);
            if (((em >> i) & 1u) && r < need) op[total_less + r] = base + i*64 + lane;
            running += (int)__popcll(bal);
        }
    }
}

// ---------------- EdgeConv MLP + neighbor max. 4 points/block, wave per point, lane=channel ----
template<int D>
__global__ __launch_bounds__(256) void edgeconv_kernel(const float* __restrict__ fin, int in_stride,
                                const int* __restrict__ idx,
                                const float* __restrict__ wa, const float* __restrict__ ba,
                                const float* __restrict__ wb, const float* __restrict__ bb,
                                float* __restrict__ fout, int out_stride) {
    __shared__ float sxi[4][64];
    __shared__ float sxj[4][64];
    __shared__ float sh1[4][64];
    int t = threadIdx.x;
    int w = t >> 6, lane = t & 63;
    int n = blockIdx.x * 4 + w;

    // per-lane (= output channel) register weights
    float wa2[D];                    // wa[D+d][lane]  (xj part)
#pragma unroll
    for (int d = 0; d < D; ++d) wa2[d] = wa[(size_t)(D + d)*64 + lane];
    float wbc[64];                   // wb[k][lane]
#pragma unroll
    for (int k = 0; k < 64; ++k) wbc[k] = wb[(size_t)k*64 + lane];
    float bbc = bb[lane];

    if (lane < D) sxi[w][lane] = fin[(size_t)n * in_stride + lane];
    __syncthreads();

    float basec = ba[lane];
#pragma unroll
    for (int d = 0; d < D; ++d) basec += sxi[w][d] * (wa[(size_t)d*64 + lane] - wa2[d]);

    float maxv = -3.4e38f;
    for (int jj = 0; jj < KNN; ++jj) {
        int j = idx[n*KNN + jj];
        if (lane < D) sxj[w][lane] = fin[(size_t)j * in_stride + lane];
        __syncthreads();
        float h = basec;
        if constexpr (D % 4 == 0) {
#pragma unroll
            for (int d = 0; d < D; d += 4) {
                float4 x4 = *reinterpret_cast<const float4*>(&sxj[w][d]);
                h += x4.x*wa2[d] + x4.y*wa2[d+1] + x4.z*wa2[d+2] + x4.w*wa2[d+3];
            }
        } else {
#pragma unroll
            for (int d = 0; d < D; ++d) h += sxj[w][d]*wa2[d];
        }
        h = fmaxf(h, 0.f);
        sh1[w][lane] = h;
        __syncthreads();
        float h2 = bbc;
#pragma unroll
        for (int k = 0; k < 64; k += 4) {
            float4 h4 = *reinterpret_cast<const float4*>(&sh1[w][k]);
            h2 += h4.x*wbc[k] + h4.y*wbc[k+1] + h4.z*wbc[k+2] + h4.w*wbc[k+3];
        }
        maxv = fmaxf(maxv, h2);
        __syncthreads();
    }
    fout[(size_t)n * out_stride + lane] = maxv;
}

// ---------------- fused head MLP: 192 -> 1024 -> 512 -> 128, 32 rows/block ----------------
__global__ __launch_bounds__(256) void head_kernel(const float* __restrict__ feat,
                            const float* __restrict__ hw1, const float* __restrict__ hb1,
                            const float* __restrict__ hw2, const float* __restrict__ hb2,
                            const float* __restrict__ hw3, const float* __restrict__ hb3,
                            float* __restrict__ out) {
    __shared__ float smem[16384];        // 64 KB union
    float* sfeat = smem;                 // [32][192]
    float* sh1   = smem + 32*192;        // [32][64]
    int t = threadIdx.x;
    int row0 = blockIdx.x * 32;

    for (int i = t; i < 32*192; i += 256) sfeat[i] = feat[(size_t)row0*192 + i];
    __syncthreads();

    float2 acc2[32];
    {
        float2 b = *reinterpret_cast<const float2*>(&hb2[2*t]);
#pragma unroll
        for (int r = 0; r < 32; ++r) acc2[r] = b;
    }
    int col = t & 63, rg = t >> 6;

    for (int chunk = 0; chunk < 16; ++chunk) {
        int k0 = chunk * 64;
        float acc1[8];
        float b1 = hb1[k0 + col];
#pragma unroll
        for (int i = 0; i < 8; ++i) acc1[i] = b1;
        for (int k = 0; k < 192; k += 4) {
            float w0 = hw1[(size_t)(k+0)*1024 + k0 + col];
            float w1 = hw1[(size_t)(k+1)*1024 + k0 + col];
            float w2 = hw1[(size_t)(k+2)*1024 + k0 + col];
            float w3 = hw1[(size_t)(k+3)*1024 + k0 + col];
#pragma unroll
            for (int i = 0; i < 8; ++i) {
                float4 fv = *reinterpret_cast<const float4*>(&sfeat[(rg + 4*i)*192 + k]);
                acc1[i] += fv.x*w0 + fv.y*w1 + fv.z*w2 + fv.w*w3;
            }
        }
#pragma unroll
        for (int i = 0; i < 8; ++i) sh1[(rg + 4*i)*64 + col] = fmaxf(acc1[i], 0.f);
        __syncthreads();
        for (int k = 0; k < 64; k += 4) {
            float2 wv[4];
#pragma unroll
            for (int q = 0; q < 4; ++q)
                wv[q] = *reinterpret_cast<const float2*>(&hw2[(size_t)(k0 + k + q)*512 + 2*t]);
#pragma unroll
            for (int r = 0; r < 32; ++r) {
                float4 h4 = *reinterpret_cast<const float4*>(&sh1[r*64 + k]);
                acc2[r].x += h4.x*wv[0].x + h4.y*wv[1].x + h4.z*wv[2].x + h4.w*wv[3].x;
                acc2[r].y += h4.x*wv[0].y + h4.y*wv[1].y + h4.z*wv[2].y + h4.w*wv[3].y;
            }
        }
        __syncthreads();
    }

    // write relu(h2) into sh2 = smem[32][512] (overlays sfeat/sh1; all reads done)
#pragma unroll
    for (int r = 0; r < 32; ++r) {
        float2 v; v.x = fmaxf(acc2[r].x, 0.f); v.y = fmaxf(acc2[r].y, 0.f);
        *reinterpret_cast<float2*>(&smem[r*512 + 2*t]) = v;
    }
    __syncthreads();

    int c3 = t & 127, rg2 = t >> 7;
    float acc3[16];
    float b3 = hb3[c3];
#pragma unroll
    for (int i = 0; i < 16; ++i) acc3[i] = b3;
    for (int k = 0; k < 512; k += 4) {
        float w0 = hw3[(size_t)(k+0)*128 + c3];
        float w1 = hw3[(size_t)(k+1)*128 + c3];
        float w2 = hw3[(size_t)(k+2)*128 + c3];
        float w3v = hw3[(size_t)(k+3)*128 + c3];
#pragma unroll
        for (int i = 0; i < 16; ++i) {
            float4 h4 = *reinterpret_cast<const float4*>(&smem[(rg2 + 2*i)*512 + k]);
            acc3[i] += h4.x*w0 + h4.y*w1 + h4.z*w2 + h4.w*w3v;
        }
    }
#pragma unroll
    for (int i = 0; i < 16; ++i)
        out[(size_t)(row0 + rg2 + 2*i)*128 + c3] = acc3[i];
}

extern "C" void kernel_launch(void* const* d_in, const int* in_sizes, int n_in,
                              void* d_out, int out_size, void* d_ws, size_t ws_size,
                              hipStream_t stream) {
    (void)in_sizes; (void)n_in; (void)out_size; (void)ws_size;
    const float* x   = (const float*)d_in[0];
    const float* pos = (const float*)d_in[1];
    const float* w1a = (const float*)d_in[2];
    const float* b1a = (const float*)d_in[3];
    const float* w1b = (const float*)d_in[4];
    const float* b1b = (const float*)d_in[5];
    const float* w2a = (const float*)d_in[6];
    const float* b2a = (const float*)d_in[7];
    const float* w2b = (const float*)d_in[8];
    const float* b2b = (const float*)d_in[9];
    const float* w3a = (const float*)d_in[10];
    const float* b3a = (const float*)d_in[11];
    const float* w3b = (const float*)d_in[12];
    const float* b3b = (const float*)d_in[13];
    const float* hw1 = (const float*)d_in[14];
    const float* hb1 = (const float*)d_in[15];
    const float* hw2 = (const float*)d_in[16];
    const float* hb2 = (const float*)d_in[17];
    const float* hw3 = (const float*)d_in[18];
    const float* hb3 = (const float*)d_in[19];
    float* out = (float*)d_out;

    float* ws   = (float*)d_ws;
    float* x0   = ws;                     // 16384*6
    float* feat = x0 + (size_t)NPTS*6;    // 16384*192  (x1|x2|x3)
    float* d2b  = feat + (size_t)NPTS*192;
    int*   idxb = (int*)(d2b + NPTS);     // 16384*30

    concat_kernel<<<NPTS/256, 256, 0, stream>>>(x, pos, x0);

    d2_kernel<6><<<NPTS/256, 256, 0, stream>>>(x0, 6, d2b);
    knn4_kernel<6><<<NPTS/4, 256, 0, stream>>>(x0, 6, d2b, idxb);
    edgeconv_kernel<6><<<NPTS/4, 256, 0, stream>>>(x0, 6, idxb, w1a, b1a, w1b, b1b, feat, 192);

    d2_kernel<64><<<NPTS/256, 256, 0, stream>>>(feat, 192, d2b);
    knn4_kernel<64><<<NPTS/4, 256, 0, stream>>>(feat, 192, d2b, idxb);
    edgeconv_kernel<64><<<NPTS/4, 256, 0, stream>>>(feat, 192, idxb, w2a, b2a, w2b, b2b, feat + 64, 192);

    d2_kernel<64><<<NPTS/256, 256, 0, stream>>>(feat + 64, 192, d2b);
    knn4_kernel<64><<<NPTS/4, 256, 0, stream>>>(feat + 64, 192, d2b, idxb);
    edgeconv_kernel<64><<<NPTS/4, 256, 0, stream>>>(feat + 64, 192, idxb, w3a, b3a, w3b, b3b, feat + 128, 192);

    head_kernel<<<NPTS/32, 256, 0, stream>>>(feat, hw1, hb1, hw2, hb2, hw3, hb3, out);
}

// Round 3
// 1759.469 us; speedup vs baseline: 2.0729x; 1.6084x over previous
//
#include <hip/hip_runtime.h>
#include <math.h>

#define BATCH 8
#define NPER 2048
#define NPTS (BATCH*NPER)   // 16384
#define KNN 30

// ---------------- concat x,pos -> x0 (NPTS x 6) ----------------
__global__ void concat_kernel(const float* __restrict__ x, const float* __restrict__ pos,
                              float* __restrict__ x0) {
    int n = blockIdx.x * blockDim.x + threadIdx.x;
    if (n >= NPTS) return;
#pragma unroll
    for (int d = 0; d < 3; ++d) {
        x0[n*6 + d]     = x[n*3 + d];
        x0[n*6 + 3 + d] = pos[n*3 + d];
    }
}

// ---------------- squared norms ----------------
template<int D>
__global__ void d2_kernel(const float* __restrict__ f, int stride, float* __restrict__ d2) {
    int n = blockIdx.x * blockDim.x + threadIdx.x;
    if (n >= NPTS) return;
    const float* r = f + (size_t)n * stride;
    float s = 0.f;
#pragma unroll
    for (int d = 0; d < D; ++d) s += r[d]*r[d];
    d2[n] = s;
}

// ---------------- kNN: block = 4 query points; shared distance compute, wave-parallel
// ---------------- radix-2 selection of the 30-smallest SET (tie: lowest idx, = top_k) ----
template<int D>
__global__ __launch_bounds__(256, 4) void knn4_kernel(const float* __restrict__ f, int stride,
                                                      const float* __restrict__ d2,
                                                      int* __restrict__ idx) {
    __shared__ float sdist[4][NPER];      // 32 KB
    __shared__ float sxi[4][(D+3)/4*4];
    __shared__ float sd2n[4];
    int t = threadIdx.x;
    int n0 = blockIdx.x * 4;
    int base = (n0 >> 11) << 11;          // batch start (4 consecutive pts same batch)

    if (t < 4*D) {
        int q = t / D, d = t - q*D;
        sxi[q][d] = f[(size_t)(n0 + q)*stride + d];
    }
    if (t < 4) sd2n[t] = d2[n0 + t];
    __syncthreads();

    // ---- phase 1: each thread computes one candidate's distance to all 4 queries ----
#pragma unroll 1
    for (int j = 0; j < NPER/256; ++j) {
        int ml = t + 256*j;
        int m = base + ml;
        const float* fm = f + (size_t)m*stride;
        float d2m = d2[m];
        float dot0 = 0.f, dot1 = 0.f, dot2 = 0.f, dot3 = 0.f;
        if constexpr (D % 4 == 0) {
#pragma unroll 2
            for (int d = 0; d < D; d += 4) {
                float4 a  = *reinterpret_cast<const float4*>(fm + d);
                float4 b0 = *reinterpret_cast<const float4*>(&sxi[0][d]);
                float4 b1 = *reinterpret_cast<const float4*>(&sxi[1][d]);
                float4 b2 = *reinterpret_cast<const float4*>(&sxi[2][d]);
                float4 b3 = *reinterpret_cast<const float4*>(&sxi[3][d]);
                dot0 += a.x*b0.x + a.y*b0.y + a.z*b0.z + a.w*b0.w;
                dot1 += a.x*b1.x + a.y*b1.y + a.z*b1.z + a.w*b1.w;
                dot2 += a.x*b2.x + a.y*b2.y + a.z*b2.z + a.w*b2.w;
                dot3 += a.x*b3.x + a.y*b3.y + a.z*b3.z + a.w*b3.w;
            }
        } else {
#pragma unroll
            for (int d = 0; d < D; ++d) {
                float a = fm[d];
                dot0 += a*sxi[0][d];
                dot1 += a*sxi[1][d];
                dot2 += a*sxi[2][d];
                dot3 += a*sxi[3][d];
            }
        }
        sdist[0][ml] = sd2n[0] + d2m - 2.f*dot0;
        sdist[1][ml] = sd2n[1] + d2m - 2.f*dot1;
        sdist[2][ml] = sd2n[2] + d2m - 2.f*dot2;
        sdist[3][ml] = sd2n[3] + d2m - 2.f*dot3;
    }
    __syncthreads();

    // ---- phase 2: wave w selects the 30 smallest for point n0+w, no barriers ----
    int w = t >> 6, lane = t & 63;
    int n = n0 + w;

    // load 32 dists/lane, transform to order-preserving uint keys
    unsigned u[NPER/64];
#pragma unroll
    for (int i = 0; i < NPER/64; ++i) {
        float dv = sdist[w][lane + 64*i];
        int b = __float_as_int(dv);
        u[i] = (unsigned)(b ^ ((b >> 31) | 0x80000000));
    }

    // bisection: T = largest x with count(u < x) < KNN  (== 30th-smallest key)
    unsigned T = 0u;
#pragma unroll
    for (int bit = 31; bit >= 0; --bit) {
        unsigned C = T | (1u << bit);
        int c = 0;
#pragma unroll
        for (int i = 0; i < NPER/64; ++i) c += (u[i] < C) ? 1 : 0;
#pragma unroll
        for (int off = 1; off < 64; off <<= 1) c += __shfl_xor(c, off);
        if (c < KNN) T = C;
    }

    // masks of strictly-less and equal
    unsigned lm = 0u, em = 0u;
#pragma unroll
    for (int i = 0; i < NPER/64; ++i) {
        lm |= (u[i] < T)  ? (1u << i) : 0u;
        em |= (u[i] == T) ? (1u << i) : 0u;
    }
    int nl = __popc(lm);
    // wave exclusive prefix over nl
    int inc = nl;
#pragma unroll
    for (int off = 1; off < 64; off <<= 1) {
        int y = __shfl_up(inc, off);
        if (lane >= off) inc += y;
    }
    int excl = inc - nl;
    int total_less = __shfl(inc, 63);

    int* op = idx + (size_t)n * KNN;
    int slot = excl;
#pragma unroll
    for (int i = 0; i < NPER/64; ++i) {
        if (lm & (1u << i)) { op[slot] = base + i*64 + lane; ++slot; }
    }

    // fill remaining with lowest-index equals (candidate idx = i*64 + lane, ascending)
    int need = KNN - total_less;
    int running = 0;
#pragma unroll
    for (int i = 0; i < NPER/64; ++i) {
        unsigned long long bal = __ballot((em >> i) & 1u);
        if (bal) {
            unsigned long long lt = bal & ((1ull << lane) - 1ull);
            int r = running + __popcll(lt);
            if (((em >> i) & 1u) && r < need) op[total_less + r] = base + i*64 + lane;
            running += (int)__popcll(bal);
        }
    }
}

// ---------------- EdgeConv MLP + neighbor max. 4 points/block, wave per point, lane=channel ----
template<int D>
__global__ __launch_bounds__(256) void edgeconv_kernel(const float* __restrict__ fin, int in_stride,
                                const int* __restrict__ idx,
                                const float* __restrict__ wa, const float* __restrict__ ba,
                                const float* __restrict__ wb, const float* __restrict__ bb,
                                float* __restrict__ fout, int out_stride) {
    __shared__ float sxi[4][64];
    __shared__ float sxj[4][64];
    __shared__ float sh1[4][64];
    int t = threadIdx.x;
    int w = t >> 6, lane = t & 63;
    int n = blockIdx.x * 4 + w;

    float wa2[D];                    // wa[D+d][lane]  (xj part)
#pragma unroll
    for (int d = 0; d < D; ++d) wa2[d] = wa[(size_t)(D + d)*64 + lane];
    float wbc[64];                   // wb[k][lane]
#pragma unroll
    for (int k = 0; k < 64; ++k) wbc[k] = wb[(size_t)k*64 + lane];
    float bbc = bb[lane];

    if (lane < D) sxi[w][lane] = fin[(size_t)n * in_stride + lane];
    __syncthreads();

    float basec = ba[lane];
#pragma unroll
    for (int d = 0; d < D; ++d) basec += sxi[w][d] * (wa[(size_t)d*64 + lane] - wa2[d]);

    float maxv = -3.4e38f;
    for (int jj = 0; jj < KNN; ++jj) {
        int j = idx[n*KNN + jj];
        if (lane < D) sxj[w][lane] = fin[(size_t)j * in_stride + lane];
        __syncthreads();
        float h = basec;
        if constexpr (D % 4 == 0) {
#pragma unroll
            for (int d = 0; d < D; d += 4) {
                float4 x4 = *reinterpret_cast<const float4*>(&sxj[w][d]);
                h += x4.x*wa2[d] + x4.y*wa2[d+1] + x4.z*wa2[d+2] + x4.w*wa2[d+3];
            }
        } else {
#pragma unroll
            for (int d = 0; d < D; ++d) h += sxj[w][d]*wa2[d];
        }
        h = fmaxf(h, 0.f);
        sh1[w][lane] = h;
        __syncthreads();
        float h2 = bbc;
#pragma unroll
        for (int k = 0; k < 64; k += 4) {
            float4 h4 = *reinterpret_cast<const float4*>(&sh1[w][k]);
            h2 += h4.x*wbc[k] + h4.y*wbc[k+1] + h4.z*wbc[k+2] + h4.w*wbc[k+3];
        }
        maxv = fmaxf(maxv, h2);
        __syncthreads();
    }
    fout[(size_t)n * out_stride + lane] = maxv;
}

// ---------------- fused head MLP: 192 -> 1024 -> 512 -> 128, 32 rows/block ----------------
// register-blocked: L1 2col x 8row, L2 4col x 16row, L3 2col x 8row
__global__ __launch_bounds__(256) void head_kernel(const float* __restrict__ feat,
                            const float* __restrict__ hw1, const float* __restrict__ hb1,
                            const float* __restrict__ hw2, const float* __restrict__ hb2,
                            const float* __restrict__ hw3, const float* __restrict__ hb3,
                            float* __restrict__ out) {
    __shared__ float smem[16384];        // 64 KB union
    float* sfeat = smem;                 // [32][192]  (6144)
    float* sh1   = smem + 6144;          // [32][128]  (4096)
    int t = threadIdx.x;
    int row0 = blockIdx.x * 32;

    for (int i = t; i < 32*192; i += 256) sfeat[i] = feat[(size_t)row0*192 + i];
    __syncthreads();

    // L2 accumulator: rows rh+2i (i<16), cols 4*c4 .. 4*c4+3
    int c4 = t & 127, rh = t >> 7;
    float4 acc2[16];
    {
        float4 b = *reinterpret_cast<const float4*>(&hb2[4*c4]);
#pragma unroll
        for (int i = 0; i < 16; ++i) acc2[i] = b;
    }

    int c1 = t & 63, rg = t >> 6;        // L1: cols k0+c1, k0+64+c1; rows rg+4i (i<8)

    for (int chunk = 0; chunk < 8; ++chunk) {
        int k0 = chunk * 128;
        // ---- layer 1: compute h1[32][128] chunk ----
        float acc1a[8], acc1b[8];
        {
            float ba_ = hb1[k0 + c1], bb_ = hb1[k0 + 64 + c1];
#pragma unroll
            for (int i = 0; i < 8; ++i) { acc1a[i] = ba_; acc1b[i] = bb_; }
        }
#pragma unroll 1
        for (int k = 0; k < 192; k += 4) {
            float wA0 = hw1[(size_t)(k+0)*1024 + k0 + c1];
            float wA1 = hw1[(size_t)(k+1)*1024 + k0 + c1];
            float wA2 = hw1[(size_t)(k+2)*1024 + k0 + c1];
            float wA3 = hw1[(size_t)(k+3)*1024 + k0 + c1];
            float wB0 = hw1[(size_t)(k+0)*1024 + k0 + 64 + c1];
            float wB1 = hw1[(size_t)(k+1)*1024 + k0 + 64 + c1];
            float wB2 = hw1[(size_t)(k+2)*1024 + k0 + 64 + c1];
            float wB3 = hw1[(size_t)(k+3)*1024 + k0 + 64 + c1];
#pragma unroll
            for (int i = 0; i < 8; ++i) {
                float4 fv = *reinterpret_cast<const float4*>(&sfeat[(rg + 4*i)*192 + k]);
                acc1a[i] += fv.x*wA0 + fv.y*wA1 + fv.z*wA2 + fv.w*wA3;
                acc1b[i] += fv.x*wB0 + fv.y*wB1 + fv.z*wB2 + fv.w*wB3;
            }
        }
#pragma unroll
        for (int i = 0; i < 8; ++i) {
            sh1[(rg + 4*i)*128 + c1]      = fmaxf(acc1a[i], 0.f);
            sh1[(rg + 4*i)*128 + 64 + c1] = fmaxf(acc1b[i], 0.f);
        }
        __syncthreads();

        // ---- layer 2: consume h1 chunk into acc2 ----
        float4 wn[4];
#pragma unroll
        for (int q = 0; q < 4; ++q)
            wn[q] = *reinterpret_cast<const float4*>(&hw2[(size_t)(k0 + q)*512 + 4*c4]);
#pragma unroll 1
        for (int k = 0; k < 128; k += 4) {
            float4 wv[4];
#pragma unroll
            for (int q = 0; q < 4; ++q) wv[q] = wn[q];
            if (k + 4 < 128) {
#pragma unroll
                for (int q = 0; q < 4; ++q)
                    wn[q] = *reinterpret_cast<const float4*>(&hw2[(size_t)(k0 + k + 4 + q)*512 + 4*c4]);
            }
#pragma unroll
            for (int i = 0; i < 16; ++i) {
                float4 h4 = *reinterpret_cast<const float4*>(&sh1[(rh + 2*i)*128 + k]);
                acc2[i].x += h4.x*wv[0].x + h4.y*wv[1].x + h4.z*wv[2].x + h4.w*wv[3].x;
                acc2[i].y += h4.x*wv[0].y + h4.y*wv[1].y + h4.z*wv[2].y + h4.w*wv[3].y;
                acc2[i].z += h4.x*wv[0].z + h4.y*wv[1].z + h4.z*wv[2].z + h4.w*wv[3].z;
                acc2[i].w += h4.x*wv[0].w + h4.y*wv[1].w + h4.z*wv[2].w + h4.w*wv[3].w;
            }
        }
        __syncthreads();
    }

    // write relu(h2) into smem[32][512] (overlays everything; all reads done)
#pragma unroll
    for (int i = 0; i < 16; ++i) {
        float4 v;
        v.x = fmaxf(acc2[i].x, 0.f); v.y = fmaxf(acc2[i].y, 0.f);
        v.z = fmaxf(acc2[i].z, 0.f); v.w = fmaxf(acc2[i].w, 0.f);
        *reinterpret_cast<float4*>(&smem[(rh + 2*i)*512 + 4*c4]) = v;
    }
    __syncthreads();

    // ---- layer 3: rows rg3+4i (i<8), cols c3, c3+64 ----
    int c3 = t & 63, rg3 = t >> 6;
    float acc3a[8], acc3b[8];
    {
        float ba_ = hb3[c3], bb_ = hb3[c3 + 64];
#pragma unroll
        for (int i = 0; i < 8; ++i) { acc3a[i] = ba_; acc3b[i] = bb_; }
    }
#pragma unroll 1
    for (int k = 0; k < 512; k += 4) {
        float wA0 = hw3[(size_t)(k+0)*128 + c3];
        float wA1 = hw3[(size_t)(k+1)*128 + c3];
        float wA2 = hw3[(size_t)(k+2)*128 + c3];
        float wA3 = hw3[(size_t)(k+3)*128 + c3];
        float wB0 = hw3[(size_t)(k+0)*128 + c3 + 64];
        float wB1 = hw3[(size_t)(k+1)*128 + c3 + 64];
        float wB2 = hw3[(size_t)(k+2)*128 + c3 + 64];
        float wB3 = hw3[(size_t)(k+3)*128 + c3 + 64];
#pragma unroll
        for (int i = 0; i < 8; ++i) {
            float4 h4 = *reinterpret_cast<const float4*>(&smem[(rg3 + 4*i)*512 + k]);
            acc3a[i] += h4.x*wA0 + h4.y*wA1 + h4.z*wA2 + h4.w*wA3;
            acc3b[i] += h4.x*wB0 + h4.y*wB1 + h4.z*wB2 + h4.w*wB3;
        }
    }
#pragma unroll
    for (int i = 0; i < 8; ++i) {
        out[(size_t)(row0 + rg3 + 4*i)*128 + c3]      = acc3a[i];
        out[(size_t)(row0 + rg3 + 4*i)*128 + c3 + 64] = acc3b[i];
    }
}

extern "C" void kernel_launch(void* const* d_in, const int* in_sizes, int n_in,
                              void* d_out, int out_size, void* d_ws, size_t ws_size,
                              hipStream_t stream) {
    (void)in_sizes; (void)n_in; (void)out_size; (void)ws_size;
    const float* x   = (const float*)d_in[0];
    const float* pos = (const float*)d_in[1];
    const float* w1a = (const float*)d_in[2];
    const float* b1a = (const float*)d_in[3];
    const float* w1b = (const float*)d_in[4];
    const float* b1b = (const float*)d_in[5];
    const float* w2a = (const float*)d_in[6];
    const float* b2a = (const float*)d_in[7];
    const float* w2b = (const float*)d_in[8];
    const float* b2b = (const float*)d_in[9];
    const float* w3a = (const float*)d_in[10];
    const float* b3a = (const float*)d_in[11];
    const float* w3b = (const float*)d_in[12];
    const float* b3b = (const float*)d_in[13];
    const float* hw1 = (const float*)d_in[14];
    const float* hb1 = (const float*)d_in[15];
    const float* hw2 = (const float*)d_in[16];
    const float* hb2 = (const float*)d_in[17];
    const float* hw3 = (const float*)d_in[18];
    const float* hb3 = (const float*)d_in[19];
    float* out = (float*)d_out;

    float* ws   = (float*)d_ws;
    float* x0   = ws;                     // 16384*6
    float* feat = x0 + (size_t)NPTS*6;    // 16384*192  (x1|x2|x3)
    float* d2b  = feat + (size_t)NPTS*192;
    int*   idxb = (int*)(d2b + NPTS);     // 16384*30

    concat_kernel<<<NPTS/256, 256, 0, stream>>>(x, pos, x0);

    d2_kernel<6><<<NPTS/256, 256, 0, stream>>>(x0, 6, d2b);
    knn4_kernel<6><<<NPTS/4, 256, 0, stream>>>(x0, 6, d2b, idxb);
    edgeconv_kernel<6><<<NPTS/4, 256, 0, stream>>>(x0, 6, idxb, w1a, b1a, w1b, b1b, feat, 192);

    d2_kernel<64><<<NPTS/256, 256, 0, stream>>>(feat, 192, d2b);
    knn4_kernel<64><<<NPTS/4, 256, 0, stream>>>(feat, 192, d2b, idxb);
    edgeconv_kernel<64><<<NPTS/4, 256, 0, stream>>>(feat, 192, idxb, w2a, b2a, w2b, b2b, feat + 64, 192);

    d2_kernel<64><<<NPTS/256, 256, 0, stream>>>(feat + 64, 192, d2b);
    knn4_kernel<64><<<NPTS/4, 256, 0, stream>>>(feat + 64, 192, d2b, idxb);
    edgeconv_kernel<64><<<NPTS/4, 256, 0, stream>>>(feat + 64, 192, idxb, w3a, b3a, w3b, b3b, feat + 128, 192);

    head_kernel<<<NPTS/32, 256, 0, stream>>>(feat, hw1, hb1, hw2, hb2, hw3, hb3, out);
}

// Round 4
// 1653.621 us; speedup vs baseline: 2.2056x; 1.0640x over previous
//
#include <hip/hip_runtime.h>
#include <math.h>

#define BATCH 8
#define NPER 2048
#define NPTS (BATCH*NPER)   // 16384
#define KNN 30

// ---------------- concat x,pos -> x0 (NPTS x 6) ----------------
__global__ void concat_kernel(const float* __restrict__ x, const float* __restrict__ pos,
                              float* __restrict__ x0) {
    int n = blockIdx.x * blockDim.x + threadIdx.x;
    if (n >= NPTS) return;
#pragma unroll
    for (int d = 0; d < 3; ++d) {
        x0[n*6 + d]     = x[n*3 + d];
        x0[n*6 + 3 + d] = pos[n*3 + d];
    }
}

// ---------------- squared norms ----------------
template<int D>
__global__ void d2_kernel(const float* __restrict__ f, int stride, float* __restrict__ d2) {
    int n = blockIdx.x * blockDim.x + threadIdx.x;
    if (n >= NPTS) return;
    const float* r = f + (size_t)n * stride;
    float s = 0.f;
#pragma unroll
    for (int d = 0; d < D; ++d) s += r[d]*r[d];
    d2[n] = s;
}

// ---------------- kNN: block = 4 query points; shared distance compute, wave-parallel
// ---------------- radix-2 selection of the 30-smallest SET (tie: lowest idx, = top_k) ----
template<int D>
__global__ __launch_bounds__(256, 4) void knn4_kernel(const float* __restrict__ f, int stride,
                                                      const float* __restrict__ d2,
                                                      int* __restrict__ idx) {
    __shared__ float sdist[4][NPER];      // 32 KB
    __shared__ float sxi[4][(D+3)/4*4];
    __shared__ float sd2n[4];
    int t = threadIdx.x;
    int n0 = blockIdx.x * 4;
    int base = (n0 >> 11) << 11;          // batch start (4 consecutive pts same batch)

    if (t < 4*D) {
        int q = t / D, d = t - q*D;
        sxi[q][d] = f[(size_t)(n0 + q)*stride + d];
    }
    if (t < 4) sd2n[t] = d2[n0 + t];
    __syncthreads();

    // ---- phase 1: each thread computes one candidate's distance to all 4 queries ----
#pragma unroll 1
    for (int j = 0; j < NPER/256; ++j) {
        int ml = t + 256*j;
        int m = base + ml;
        const float* fm = f + (size_t)m*stride;
        float d2m = d2[m];
        float dot0 = 0.f, dot1 = 0.f, dot2 = 0.f, dot3 = 0.f;
        if constexpr (D % 4 == 0) {
#pragma unroll 2
            for (int d = 0; d < D; d += 4) {
                float4 a  = *reinterpret_cast<const float4*>(fm + d);
                float4 b0 = *reinterpret_cast<const float4*>(&sxi[0][d]);
                float4 b1 = *reinterpret_cast<const float4*>(&sxi[1][d]);
                float4 b2 = *reinterpret_cast<const float4*>(&sxi[2][d]);
                float4 b3 = *reinterpret_cast<const float4*>(&sxi[3][d]);
                dot0 += a.x*b0.x + a.y*b0.y + a.z*b0.z + a.w*b0.w;
                dot1 += a.x*b1.x + a.y*b1.y + a.z*b1.z + a.w*b1.w;
                dot2 += a.x*b2.x + a.y*b2.y + a.z*b2.z + a.w*b2.w;
                dot3 += a.x*b3.x + a.y*b3.y + a.z*b3.z + a.w*b3.w;
            }
        } else {
#pragma unroll
            for (int d = 0; d < D; ++d) {
                float a = fm[d];
                dot0 += a*sxi[0][d];
                dot1 += a*sxi[1][d];
                dot2 += a*sxi[2][d];
                dot3 += a*sxi[3][d];
            }
        }
        sdist[0][ml] = sd2n[0] + d2m - 2.f*dot0;
        sdist[1][ml] = sd2n[1] + d2m - 2.f*dot1;
        sdist[2][ml] = sd2n[2] + d2m - 2.f*dot2;
        sdist[3][ml] = sd2n[3] + d2m - 2.f*dot3;
    }
    __syncthreads();

    // ---- phase 2: wave w selects the 30 smallest for point n0+w, no barriers ----
    int w = t >> 6, lane = t & 63;
    int n = n0 + w;

    unsigned u[NPER/64];
#pragma unroll
    for (int i = 0; i < NPER/64; ++i) {
        float dv = sdist[w][lane + 64*i];
        int b = __float_as_int(dv);
        u[i] = (unsigned)(b ^ ((b >> 31) | 0x80000000));
    }

    // bisection: T = largest x with count(u < x) < KNN  (== 30th-smallest key)
    unsigned T = 0u;
#pragma unroll
    for (int bit = 31; bit >= 0; --bit) {
        unsigned C = T | (1u << bit);
        int c = 0;
#pragma unroll
        for (int i = 0; i < NPER/64; ++i) c += (u[i] < C) ? 1 : 0;
#pragma unroll
        for (int off = 1; off < 64; off <<= 1) c += __shfl_xor(c, off);
        if (c < KNN) T = C;
    }

    unsigned lm = 0u, em = 0u;
#pragma unroll
    for (int i = 0; i < NPER/64; ++i) {
        lm |= (u[i] < T)  ? (1u << i) : 0u;
        em |= (u[i] == T) ? (1u << i) : 0u;
    }
    int nl = __popc(lm);
    int inc = nl;
#pragma unroll
    for (int off = 1; off < 64; off <<= 1) {
        int y = __shfl_up(inc, off);
        if (lane >= off) inc += y;
    }
    int excl = inc - nl;
    int total_less = __shfl(inc, 63);

    int* op = idx + (size_t)n * KNN;
    int slot = excl;
#pragma unroll
    for (int i = 0; i < NPER/64; ++i) {
        if (lm & (1u << i)) { op[slot] = base + i*64 + lane; ++slot; }
    }

    int need = KNN - total_less;
    int running = 0;
#pragma unroll
    for (int i = 0; i < NPER/64; ++i) {
        unsigned long long bal = __ballot((em >> i) & 1u);
        if (bal) {
            unsigned long long lt = bal & ((1ull << lane) - 1ull);
            int r = running + __popcll(lt);
            if (((em >> i) & 1u) && r < need) op[total_less + r] = base + i*64 + lane;
            running += (int)__popcll(bal);
        }
    }
}

// ---------------- G = F @ waB  (waB = rows D..2D-1 of wa), G is [NPTS][64] ----------------
template<int D>
__global__ __launch_bounds__(256) void gmat_kernel(const float* __restrict__ fin, int in_stride,
                                                   const float* __restrict__ wa,
                                                   float* __restrict__ G) {
    constexpr int DP = (D+3)/4*4;
    __shared__ float sF[64][DP];
    int t = threadIdx.x;
    int row0 = blockIdx.x * 64;
    for (int i = t; i < 64*D; i += 256) {
        int r = i / D, c = i - r*D;
        sF[r][c] = fin[(size_t)(row0 + r)*in_stride + c];
    }
    int w = t >> 6, lane = t & 63;
    float wreg[D];
#pragma unroll
    for (int d = 0; d < D; ++d) wreg[d] = wa[(size_t)(D + d)*64 + lane];
    __syncthreads();
#pragma unroll 1
    for (int pi = 0; pi < 16; ++pi) {
        int p = w*16 + pi;
        float acc = 0.f;
        if constexpr (D % 4 == 0) {
#pragma unroll
            for (int d = 0; d < D; d += 4) {
                float4 fv = *reinterpret_cast<const float4*>(&sF[p][d]);
                acc += fv.x*wreg[d] + fv.y*wreg[d+1] + fv.z*wreg[d+2] + fv.w*wreg[d+3];
            }
        } else {
#pragma unroll
            for (int d = 0; d < D; ++d) acc += sF[p][d]*wreg[d];
        }
        G[(size_t)(row0 + p)*64 + lane] = acc;
    }
}

// ---------------- EdgeConv v2: h1 = relu(base + G[j]); h2 = h1@wb; max over j ----------------
template<int D>
__global__ __launch_bounds__(256) void edgeconv2_kernel(const float* __restrict__ fin, int in_stride,
                                const float* __restrict__ G,
                                const int* __restrict__ idx,
                                const float* __restrict__ wa, const float* __restrict__ ba,
                                const float* __restrict__ wb, const float* __restrict__ bb,
                                float* __restrict__ fout, int out_stride) {
    __shared__ float sxi[4][(D+3)/4*4];
    __shared__ float sh1[4][2][64];
    int t = threadIdx.x;
    int w = t >> 6, lane = t & 63;
    int n = blockIdx.x * 4 + w;

    float wbc[64];
#pragma unroll
    for (int k = 0; k < 64; ++k) wbc[k] = wb[(size_t)k*64 + lane];
    float bbc = bb[lane];

    if (lane < D) sxi[w][lane] = fin[(size_t)n * in_stride + lane];
    __syncthreads();

    float basec = ba[lane];
#pragma unroll
    for (int d = 0; d < D; ++d)
        basec += sxi[w][d] * (wa[(size_t)d*64 + lane] - wa[(size_t)(D + d)*64 + lane]);

    const int* ip = idx + (size_t)n * KNN;
    int2 jp = *reinterpret_cast<const int2*>(ip);
    float g0 = G[(size_t)jp.x*64 + lane];
    float g1 = G[(size_t)jp.y*64 + lane];
    float maxv = -3.4e38f;
#pragma unroll 1
    for (int jj = 0; jj < KNN; jj += 2) {
        sh1[w][0][lane] = fmaxf(basec + g0, 0.f);
        sh1[w][1][lane] = fmaxf(basec + g1, 0.f);
        int2 jn;
        bool more = (jj + 2 < KNN);
        if (more) jn = *reinterpret_cast<const int2*>(ip + jj + 2);
        __syncthreads();
        if (more) {
            g0 = G[(size_t)jn.x*64 + lane];
            g1 = G[(size_t)jn.y*64 + lane];
        }
        float h20 = bbc, h21 = bbc;
#pragma unroll
        for (int k = 0; k < 64; k += 4) {
            float4 a = *reinterpret_cast<const float4*>(&sh1[w][0][k]);
            float4 b = *reinterpret_cast<const float4*>(&sh1[w][1][k]);
            h20 += a.x*wbc[k] + a.y*wbc[k+1] + a.z*wbc[k+2] + a.w*wbc[k+3];
            h21 += b.x*wbc[k] + b.y*wbc[k+1] + b.z*wbc[k+2] + b.w*wbc[k+3];
        }
        maxv = fmaxf(maxv, fmaxf(h20, h21));
        __syncthreads();
    }
    fout[(size_t)n * out_stride + lane] = maxv;
}

// ---------------- fused head MLP: 192 -> 1024 -> 512 -> 128, 32 rows/block ----------------
// L1: 4col(float4) x 4row;  L2: 4col(float4) x 16row prefetched;  L3: 4col(float4) x 4row
__global__ __launch_bounds__(256) void head_kernel(const float* __restrict__ feat,
                            const float* __restrict__ hw1, const float* __restrict__ hb1,
                            const float* __restrict__ hw2, const float* __restrict__ hb2,
                            const float* __restrict__ hw3, const float* __restrict__ hb3,
                            float* __restrict__ out) {
    __shared__ float smem[16384];        // 64 KB union
    float* sfeat = smem;                 // [32][192]  (6144)
    float* sh1   = smem + 6144;          // [32][128]  (4096)
    int t = threadIdx.x;
    int row0 = blockIdx.x * 32;

    for (int i = t; i < 32*192; i += 256) sfeat[i] = feat[(size_t)row0*192 + i];
    __syncthreads();

    int c4 = t & 127, rh = t >> 7;       // L2: cols 4*c4.., rows rh+2i (i<16)
    float4 acc2[16];
    {
        float4 b = *reinterpret_cast<const float4*>(&hb2[4*c4]);
#pragma unroll
        for (int i = 0; i < 16; ++i) acc2[i] = b;
    }

    int cg = t & 31, rg = t >> 5;        // L1/L3: cols cg*4.., rows rg+8i (i<4)

    for (int chunk = 0; chunk < 8; ++chunk) {
        int k0 = chunk * 128;
        // ---- layer 1: h1[32][128] chunk ----
        float4 acc1[4];
        {
            float4 b = *reinterpret_cast<const float4*>(&hb1[k0 + cg*4]);
#pragma unroll
            for (int i = 0; i < 4; ++i) acc1[i] = b;
        }
#pragma unroll 2
        for (int k = 0; k < 192; k += 4) {
            float4 wv0 = *reinterpret_cast<const float4*>(&hw1[(size_t)(k+0)*1024 + k0 + cg*4]);
            float4 wv1 = *reinterpret_cast<const float4*>(&hw1[(size_t)(k+1)*1024 + k0 + cg*4]);
            float4 wv2 = *reinterpret_cast<const float4*>(&hw1[(size_t)(k+2)*1024 + k0 + cg*4]);
            float4 wv3 = *reinterpret_cast<const float4*>(&hw1[(size_t)(k+3)*1024 + k0 + cg*4]);
#pragma unroll
            for (int i = 0; i < 4; ++i) {
                float4 fv = *reinterpret_cast<const float4*>(&sfeat[(rg + 8*i)*192 + k]);
                acc1[i].x += fv.x*wv0.x + fv.y*wv1.x + fv.z*wv2.x + fv.w*wv3.x;
                acc1[i].y += fv.x*wv0.y + fv.y*wv1.y + fv.z*wv2.y + fv.w*wv3.y;
                acc1[i].z += fv.x*wv0.z + fv.y*wv1.z + fv.z*wv2.z + fv.w*wv3.z;
                acc1[i].w += fv.x*wv0.w + fv.y*wv1.w + fv.z*wv2.w + fv.w*wv3.w;
            }
        }
#pragma unroll
        for (int i = 0; i < 4; ++i) {
            float4 v;
            v.x = fmaxf(acc1[i].x, 0.f); v.y = fmaxf(acc1[i].y, 0.f);
            v.z = fmaxf(acc1[i].z, 0.f); v.w = fmaxf(acc1[i].w, 0.f);
            *reinterpret_cast<float4*>(&sh1[(rg + 8*i)*128 + cg*4]) = v;
        }
        __syncthreads();

        // ---- layer 2: consume h1 chunk ----
        float4 wn[4];
#pragma unroll
        for (int q = 0; q < 4; ++q)
            wn[q] = *reinterpret_cast<const float4*>(&hw2[(size_t)(k0 + q)*512 + 4*c4]);
#pragma unroll 1
        for (int k = 0; k < 128; k += 4) {
            float4 wv[4];
#pragma unroll
            for (int q = 0; q < 4; ++q) wv[q] = wn[q];
            if (k + 4 < 128) {
#pragma unroll
                for (int q = 0; q < 4; ++q)
                    wn[q] = *reinterpret_cast<const float4*>(&hw2[(size_t)(k0 + k + 4 + q)*512 + 4*c4]);
            }
#pragma unroll
            for (int i = 0; i < 16; ++i) {
                float4 h4 = *reinterpret_cast<const float4*>(&sh1[(rh + 2*i)*128 + k]);
                acc2[i].x += h4.x*wv[0].x + h4.y*wv[1].x + h4.z*wv[2].x + h4.w*wv[3].x;
                acc2[i].y += h4.x*wv[0].y + h4.y*wv[1].y + h4.z*wv[2].y + h4.w*wv[3].y;
                acc2[i].z += h4.x*wv[0].z + h4.y*wv[1].z + h4.z*wv[2].z + h4.w*wv[3].z;
                acc2[i].w += h4.x*wv[0].w + h4.y*wv[1].w + h4.z*wv[2].w + h4.w*wv[3].w;
            }
        }
        __syncthreads();
    }

    // write relu(h2) into smem[32][512]
#pragma unroll
    for (int i = 0; i < 16; ++i) {
        float4 v;
        v.x = fmaxf(acc2[i].x, 0.f); v.y = fmaxf(acc2[i].y, 0.f);
        v.z = fmaxf(acc2[i].z, 0.f); v.w = fmaxf(acc2[i].w, 0.f);
        *reinterpret_cast<float4*>(&smem[(rh + 2*i)*512 + 4*c4]) = v;
    }
    __syncthreads();

    // ---- layer 3 ----
    float4 acc3[4];
    {
        float4 b = *reinterpret_cast<const float4*>(&hb3[cg*4]);
#pragma unroll
        for (int i = 0; i < 4; ++i) acc3[i] = b;
    }
#pragma unroll 2
    for (int k = 0; k < 512; k += 4) {
        float4 wv0 = *reinterpret_cast<const float4*>(&hw3[(size_t)(k+0)*128 + cg*4]);
        float4 wv1 = *reinterpret_cast<const float4*>(&hw3[(size_t)(k+1)*128 + cg*4]);
        float4 wv2 = *reinterpret_cast<const float4*>(&hw3[(size_t)(k+2)*128 + cg*4]);
        float4 wv3 = *reinterpret_cast<const float4*>(&hw3[(size_t)(k+3)*128 + cg*4]);
#pragma unroll
        for (int i = 0; i < 4; ++i) {
            float4 h4 = *reinterpret_cast<const float4*>(&smem[(rg + 8*i)*512 + k]);
            acc3[i].x += h4.x*wv0.x + h4.y*wv1.x + h4.z*wv2.x + h4.w*wv3.x;
            acc3[i].y += h4.x*wv0.y + h4.y*wv1.y + h4.z*wv2.y + h4.w*wv3.y;
            acc3[i].z += h4.x*wv0.z + h4.y*wv1.z + h4.z*wv2.z + h4.w*wv3.z;
            acc3[i].w += h4.x*wv0.w + h4.y*wv1.w + h4.z*wv2.w + h4.w*wv3.w;
        }
    }
#pragma unroll
    for (int i = 0; i < 4; ++i)
        *reinterpret_cast<float4*>(&out[(size_t)(row0 + rg + 8*i)*128 + cg*4]) = acc3[i];
}

extern "C" void kernel_launch(void* const* d_in, const int* in_sizes, int n_in,
                              void* d_out, int out_size, void* d_ws, size_t ws_size,
                              hipStream_t stream) {
    (void)in_sizes; (void)n_in; (void)out_size; (void)ws_size;
    const float* x   = (const float*)d_in[0];
    const float* pos = (const float*)d_in[1];
    const float* w1a = (const float*)d_in[2];
    const float* b1a = (const float*)d_in[3];
    const float* w1b = (const float*)d_in[4];
    const float* b1b = (const float*)d_in[5];
    const float* w2a = (const float*)d_in[6];
    const float* b2a = (const float*)d_in[7];
    const float* w2b = (const float*)d_in[8];
    const float* b2b = (const float*)d_in[9];
    const float* w3a = (const float*)d_in[10];
    const float* b3a = (const float*)d_in[11];
    const float* w3b = (const float*)d_in[12];
    const float* b3b = (const float*)d_in[13];
    const float* hw1 = (const float*)d_in[14];
    const float* hb1 = (const float*)d_in[15];
    const float* hw2 = (const float*)d_in[16];
    const float* hb2 = (const float*)d_in[17];
    const float* hw3 = (const float*)d_in[18];
    const float* hb3 = (const float*)d_in[19];
    float* out = (float*)d_out;

    float* ws   = (float*)d_ws;
    float* x0   = ws;                     // 16384*6
    float* feat = x0 + (size_t)NPTS*6;    // 16384*192  (x1|x2|x3)
    float* d2b  = feat + (size_t)NPTS*192;
    int*   idxb = (int*)(d2b + NPTS);     // 16384*30
    float* G    = (float*)(idxb + (size_t)NPTS*KNN);   // 16384*64

    concat_kernel<<<NPTS/256, 256, 0, stream>>>(x, pos, x0);

    d2_kernel<6><<<NPTS/256, 256, 0, stream>>>(x0, 6, d2b);
    knn4_kernel<6><<<NPTS/4, 256, 0, stream>>>(x0, 6, d2b, idxb);
    gmat_kernel<6><<<NPTS/64, 256, 0, stream>>>(x0, 6, w1a, G);
    edgeconv2_kernel<6><<<NPTS/4, 256, 0, stream>>>(x0, 6, G, idxb, w1a, b1a, w1b, b1b, feat, 192);

    d2_kernel<64><<<NPTS/256, 256, 0, stream>>>(feat, 192, d2b);
    knn4_kernel<64><<<NPTS/4, 256, 0, stream>>>(feat, 192, d2b, idxb);
    gmat_kernel<64><<<NPTS/64, 256, 0, stream>>>(feat, 192, w2a, G);
    edgeconv2_kernel<64><<<NPTS/4, 256, 0, stream>>>(feat, 192, G, idxb, w2a, b2a, w2b, b2b, feat + 64, 192);

    d2_kernel<64><<<NPTS/256, 256, 0, stream>>>(feat + 64, 192, d2b);
    knn4_kernel<64><<<NPTS/4, 256, 0, stream>>>(feat + 64, 192, d2b, idxb);
    gmat_kernel<64><<<NPTS/64, 256, 0, stream>>>(feat + 64, 192, w3a, G);
    edgeconv2_kernel<64><<<NPTS/4, 256, 0, stream>>>(feat + 64, 192, G, idxb, w3a, b3a, w3b, b3b, feat + 128, 192);

    head_kernel<<<NPTS/32, 256, 0, stream>>>(feat, hw1, hb1, hw2, hb2, hw3, hb3, out);
}

// Round 5
// 1176.752 us; speedup vs baseline: 3.0994x; 1.4052x over previous
//
#include <hip/hip_runtime.h>
#include <math.h>

#define BATCH 8
#define NPER 2048
#define NPTS (BATCH*NPER)   // 16384
#define KNN 30

typedef __attribute__((ext_vector_type(8))) short bf16x8;
typedef __attribute__((ext_vector_type(4))) float f32x4;

__device__ __forceinline__ ushort f2bf(float x) {
    unsigned u = __float_as_uint(x);
    unsigned r = (u + 0x7fffu + ((u >> 16) & 1u)) >> 16;
    return (ushort)r;
}
__device__ __forceinline__ float bf2f(ushort h) {
    return __uint_as_float(((unsigned)h) << 16);
}

// ---------------- concat x,pos -> x0 (NPTS x 6) ----------------
__global__ void concat_kernel(const float* __restrict__ x, const float* __restrict__ pos,
                              float* __restrict__ x0) {
    int n = blockIdx.x * blockDim.x + threadIdx.x;
    if (n >= NPTS) return;
#pragma unroll
    for (int d = 0; d < 3; ++d) {
        x0[n*6 + d]     = x[n*3 + d];
        x0[n*6 + 3 + d] = pos[n*3 + d];
    }
}

// ---------------- squared norms ----------------
template<int D>
__global__ void d2_kernel(const float* __restrict__ f, int stride, float* __restrict__ d2) {
    int n = blockIdx.x * blockDim.x + threadIdx.x;
    if (n >= NPTS) return;
    const float* r = f + (size_t)n * stride;
    float s = 0.f;
#pragma unroll
    for (int d = 0; d < D; ++d) s += r[d]*r[d];
    d2[n] = s;
}

// ---------------- kNN: block = 4 query points; shared distance compute, wave-parallel
// ---------------- radix-2 selection of the 30-smallest SET (tie: lowest idx, = top_k) ----
template<int D>
__global__ __launch_bounds__(256, 4) void knn4_kernel(const float* __restrict__ f, int stride,
                                                      const float* __restrict__ d2,
                                                      int* __restrict__ idx) {
    __shared__ float sdist[4][NPER];      // 32 KB
    __shared__ float sxi[4][(D+3)/4*4];
    __shared__ float sd2n[4];
    int t = threadIdx.x;
    int n0 = blockIdx.x * 4;
    int base = (n0 >> 11) << 11;          // batch start (4 consecutive pts same batch)

    if (t < 4*D) {
        int q = t / D, d = t - q*D;
        sxi[q][d] = f[(size_t)(n0 + q)*stride + d];
    }
    if (t < 4) sd2n[t] = d2[n0 + t];
    __syncthreads();

    // ---- phase 1: each thread computes one candidate's distance to all 4 queries ----
#pragma unroll 1
    for (int j = 0; j < NPER/256; ++j) {
        int ml = t + 256*j;
        int m = base + ml;
        const float* fm = f + (size_t)m*stride;
        float d2m = d2[m];
        float dot0 = 0.f, dot1 = 0.f, dot2 = 0.f, dot3 = 0.f;
        if constexpr (D % 4 == 0) {
#pragma unroll 2
            for (int d = 0; d < D; d += 4) {
                float4 a  = *reinterpret_cast<const float4*>(fm + d);
                float4 b0 = *reinterpret_cast<const float4*>(&sxi[0][d]);
                float4 b1 = *reinterpret_cast<const float4*>(&sxi[1][d]);
                float4 b2 = *reinterpret_cast<const float4*>(&sxi[2][d]);
                float4 b3 = *reinterpret_cast<const float4*>(&sxi[3][d]);
                dot0 += a.x*b0.x + a.y*b0.y + a.z*b0.z + a.w*b0.w;
                dot1 += a.x*b1.x + a.y*b1.y + a.z*b1.z + a.w*b1.w;
                dot2 += a.x*b2.x + a.y*b2.y + a.z*b2.z + a.w*b2.w;
                dot3 += a.x*b3.x + a.y*b3.y + a.z*b3.z + a.w*b3.w;
            }
        } else {
#pragma unroll
            for (int d = 0; d < D; ++d) {
                float a = fm[d];
                dot0 += a*sxi[0][d];
                dot1 += a*sxi[1][d];
                dot2 += a*sxi[2][d];
                dot3 += a*sxi[3][d];
            }
        }
        sdist[0][ml] = sd2n[0] + d2m - 2.f*dot0;
        sdist[1][ml] = sd2n[1] + d2m - 2.f*dot1;
        sdist[2][ml] = sd2n[2] + d2m - 2.f*dot2;
        sdist[3][ml] = sd2n[3] + d2m - 2.f*dot3;
    }
    __syncthreads();

    // ---- phase 2: wave w selects the 30 smallest for point n0+w, no barriers ----
    int w = t >> 6, lane = t & 63;
    int n = n0 + w;

    unsigned u[NPER/64];
#pragma unroll
    for (int i = 0; i < NPER/64; ++i) {
        float dv = sdist[w][lane + 64*i];
        int b = __float_as_int(dv);
        u[i] = (unsigned)(b ^ ((b >> 31) | 0x80000000));
    }

    // bisection: T = largest x with count(u < x) < KNN  (== 30th-smallest key)
    unsigned T = 0u;
#pragma unroll
    for (int bit = 31; bit >= 0; --bit) {
        unsigned C = T | (1u << bit);
        int c = 0;
#pragma unroll
        for (int i = 0; i < NPER/64; ++i) c += (u[i] < C) ? 1 : 0;
#pragma unroll
        for (int off = 1; off < 64; off <<= 1) c += __shfl_xor(c, off);
        if (c < KNN) T = C;
    }

    unsigned lm = 0u, em = 0u;
#pragma unroll
    for (int i = 0; i < NPER/64; ++i) {
        lm |= (u[i] < T)  ? (1u << i) : 0u;
        em |= (u[i] == T) ? (1u << i) : 0u;
    }
    int nl = __popc(lm);
    int inc = nl;
#pragma unroll
    for (int off = 1; off < 64; off <<= 1) {
        int y = __shfl_up(inc, off);
        if (lane >= off) inc += y;
    }
    int excl = inc - nl;
    int total_less = __shfl(inc, 63);

    int* op = idx + (size_t)n * KNN;
    int slot = excl;
#pragma unroll
    for (int i = 0; i < NPER/64; ++i) {
        if (lm & (1u << i)) { op[slot] = base + i*64 + lane; ++slot; }
    }

    int need = KNN - total_less;
    int running = 0;
#pragma unroll
    for (int i = 0; i < NPER/64; ++i) {
        unsigned long long bal = __ballot((em >> i) & 1u);
        if (bal) {
            unsigned long long lt = bal & ((1ull << lane) - 1ull);
            int r = running + __popcll(lt);
            if (((em >> i) & 1u) && r < need) op[total_less + r] = base + i*64 + lane;
            running += (int)__popcll(bal);
        }
    }
}

// ---------------- G = F @ waB  (waB = rows D..2D-1 of wa), G is [NPTS][64] ----------------
template<int D>
__global__ __launch_bounds__(256) void gmat_kernel(const float* __restrict__ fin, int in_stride,
                                                   const float* __restrict__ wa,
                                                   float* __restrict__ G) {
    constexpr int DP = (D+3)/4*4;
    __shared__ float sF[64][DP];
    int t = threadIdx.x;
    int row0 = blockIdx.x * 64;
    for (int i = t; i < 64*D; i += 256) {
        int r = i / D, c = i - r*D;
        sF[r][c] = fin[(size_t)(row0 + r)*in_stride + c];
    }
    int w = t >> 6, lane = t & 63;
    float wreg[D];
#pragma unroll
    for (int d = 0; d < D; ++d) wreg[d] = wa[(size_t)(D + d)*64 + lane];
    __syncthreads();
#pragma unroll 1
    for (int pi = 0; pi < 16; ++pi) {
        int p = w*16 + pi;
        float acc = 0.f;
        if constexpr (D % 4 == 0) {
#pragma unroll
            for (int d = 0; d < D; d += 4) {
                float4 fv = *reinterpret_cast<const float4*>(&sF[p][d]);
                acc += fv.x*wreg[d] + fv.y*wreg[d+1] + fv.z*wreg[d+2] + fv.w*wreg[d+3];
            }
        } else {
#pragma unroll
            for (int d = 0; d < D; ++d) acc += sF[p][d]*wreg[d];
        }
        G[(size_t)(row0 + p)*64 + lane] = acc;
    }
}

// ---------------- EdgeConv v2: h1 = relu(base + G[j]); h2 = h1@wb; max over j ----------------
template<int D>
__global__ __launch_bounds__(256) void edgeconv2_kernel(const float* __restrict__ fin, int in_stride,
                                const float* __restrict__ G,
                                const int* __restrict__ idx,
                                const float* __restrict__ wa, const float* __restrict__ ba,
                                const float* __restrict__ wb, const float* __restrict__ bb,
                                float* __restrict__ fout, int out_stride) {
    __shared__ float sxi[4][(D+3)/4*4];
    __shared__ float sh1[4][2][64];
    int t = threadIdx.x;
    int w = t >> 6, lane = t & 63;
    int n = blockIdx.x * 4 + w;

    float wbc[64];
#pragma unroll
    for (int k = 0; k < 64; ++k) wbc[k] = wb[(size_t)k*64 + lane];
    float bbc = bb[lane];

    if (lane < D) sxi[w][lane] = fin[(size_t)n * in_stride + lane];
    __syncthreads();

    float basec = ba[lane];
#pragma unroll
    for (int d = 0; d < D; ++d)
        basec += sxi[w][d] * (wa[(size_t)d*64 + lane] - wa[(size_t)(D + d)*64 + lane]);

    const int* ip = idx + (size_t)n * KNN;
    int2 jp = *reinterpret_cast<const int2*>(ip);
    float g0 = G[(size_t)jp.x*64 + lane];
    float g1 = G[(size_t)jp.y*64 + lane];
    float maxv = -3.4e38f;
#pragma unroll 1
    for (int jj = 0; jj < KNN; jj += 2) {
        sh1[w][0][lane] = fmaxf(basec + g0, 0.f);
        sh1[w][1][lane] = fmaxf(basec + g1, 0.f);
        int2 jn;
        bool more = (jj + 2 < KNN);
        if (more) jn = *reinterpret_cast<const int2*>(ip + jj + 2);
        __syncthreads();
        if (more) {
            g0 = G[(size_t)jn.x*64 + lane];
            g1 = G[(size_t)jn.y*64 + lane];
        }
        float h20 = bbc, h21 = bbc;
#pragma unroll
        for (int k = 0; k < 64; k += 4) {
            float4 a = *reinterpret_cast<const float4*>(&sh1[w][0][k]);
            float4 b = *reinterpret_cast<const float4*>(&sh1[w][1][k]);
            h20 += a.x*wbc[k] + a.y*wbc[k+1] + a.z*wbc[k+2] + a.w*wbc[k+3];
            h21 += b.x*wbc[k] + b.y*wbc[k+1] + b.z*wbc[k+2] + b.w*wbc[k+3];
        }
        maxv = fmaxf(maxv, fmaxf(h20, h21));
        __syncthreads();
    }
    fout[(size_t)n * out_stride + lane] = maxv;
}

// ---------------- weight split: w[K][N] fp32 -> hi/lo bf16 transposed [N][K] ----------------
__global__ void wsplit_kernel(const float* __restrict__ w, int K, int N,
                              ushort* __restrict__ hi, ushort* __restrict__ lo, int total) {
    int i = blockIdx.x * 256 + threadIdx.x;
    if (i >= total) return;
    int n = i / K, k = i - n*K;
    float x = w[(size_t)k * N + n];
    ushort h = f2bf(x);
    hi[i] = h;
    lo[i] = f2bf(x - bf2f(h));
}

// ---------------- split-bf16 MFMA GEMM: C[M][N] = act(A[M][K] @ W + bias) ----------------
// W pre-split transposed [N][K] bf16 hi/lo. 64x64 tile, 4 waves, 2x2 16x16 MFMA per wave.
template<bool RELU>
__global__ __launch_bounds__(256) void mlp_gemm_kernel(
    const float* __restrict__ A, int lda, int K,
    const ushort* __restrict__ Bhi, const ushort* __restrict__ Blo,
    const float* __restrict__ bias, float* __restrict__ C, int N)
{
    __shared__ __align__(16) ushort sAh[64*40];
    __shared__ __align__(16) ushort sAl[64*40];
    __shared__ __align__(16) ushort sBh[64*40];
    __shared__ __align__(16) ushort sBl[64*40];
    int t = threadIdx.x;
    int row0 = blockIdx.x * 64;
    int n0   = blockIdx.y * 64;
    int r = t >> 2, sg = (t & 3) * 8;
    int lane = t & 63, w = t >> 6;
    int wr = w & 1, wc = w >> 1;
    int fr = lane & 15, fk = (lane >> 4) * 8;

    f32x4 acc00 = {0.f,0.f,0.f,0.f}, acc01 = {0.f,0.f,0.f,0.f};
    f32x4 acc10 = {0.f,0.f,0.f,0.f}, acc11 = {0.f,0.f,0.f,0.f};

    const int nk = K / 32;
#pragma unroll 1
    for (int kc = 0; kc < nk; ++kc) {
        int k0 = kc * 32;
        const float* ap = A + (size_t)(row0 + r) * lda + k0 + sg;
        float4 av0 = *reinterpret_cast<const float4*>(ap);
        float4 av1 = *reinterpret_cast<const float4*>(ap + 4);
        float av[8] = {av0.x,av0.y,av0.z,av0.w,av1.x,av1.y,av1.z,av1.w};
        uint ph[4], pl[4];
#pragma unroll
        for (int i = 0; i < 4; ++i) {
            ushort h0 = f2bf(av[2*i]);
            ushort l0 = f2bf(av[2*i]   - bf2f(h0));
            ushort h1 = f2bf(av[2*i+1]);
            ushort l1 = f2bf(av[2*i+1] - bf2f(h1));
            ph[i] = (uint)h0 | ((uint)h1 << 16);
            pl[i] = (uint)l0 | ((uint)l1 << 16);
        }
        uint4 bh = *reinterpret_cast<const uint4*>(Bhi + (size_t)(n0 + r) * K + k0 + sg);
        uint4 bl = *reinterpret_cast<const uint4*>(Blo + (size_t)(n0 + r) * K + k0 + sg);
        __syncthreads();   // previous chunk's frag reads done before overwrite
        *reinterpret_cast<uint4*>(&sAh[r*40 + sg]) = make_uint4(ph[0],ph[1],ph[2],ph[3]);
        *reinterpret_cast<uint4*>(&sAl[r*40 + sg]) = make_uint4(pl[0],pl[1],pl[2],pl[3]);
        *reinterpret_cast<uint4*>(&sBh[r*40 + sg]) = bh;
        *reinterpret_cast<uint4*>(&sBl[r*40 + sg]) = bl;
        __syncthreads();

        bf16x8 a0h = *reinterpret_cast<const bf16x8*>(&sAh[(wr*32 + fr)*40 + fk]);
        bf16x8 a1h = *reinterpret_cast<const bf16x8*>(&sAh[(wr*32 + 16 + fr)*40 + fk]);
        bf16x8 a0l = *reinterpret_cast<const bf16x8*>(&sAl[(wr*32 + fr)*40 + fk]);
        bf16x8 a1l = *reinterpret_cast<const bf16x8*>(&sAl[(wr*32 + 16 + fr)*40 + fk]);
        bf16x8 b0h = *reinterpret_cast<const bf16x8*>(&sBh[(wc*32 + fr)*40 + fk]);
        bf16x8 b1h = *reinterpret_cast<const bf16x8*>(&sBh[(wc*32 + 16 + fr)*40 + fk]);
        bf16x8 b0l = *reinterpret_cast<const bf16x8*>(&sBl[(wc*32 + fr)*40 + fk]);
        bf16x8 b1l = *reinterpret_cast<const bf16x8*>(&sBl[(wc*32 + 16 + fr)*40 + fk]);

        acc00 = __builtin_amdgcn_mfma_f32_16x16x32_bf16(a0h, b0h, acc00, 0, 0, 0);
        acc00 = __builtin_amdgcn_mfma_f32_16x16x32_bf16(a0h, b0l, acc00, 0, 0, 0);
        acc00 = __builtin_amdgcn_mfma_f32_16x16x32_bf16(a0l, b0h, acc00, 0, 0, 0);
        acc01 = __builtin_amdgcn_mfma_f32_16x16x32_bf16(a0h, b1h, acc01, 0, 0, 0);
        acc01 = __builtin_amdgcn_mfma_f32_16x16x32_bf16(a0h, b1l, acc01, 0, 0, 0);
        acc01 = __builtin_amdgcn_mfma_f32_16x16x32_bf16(a0l, b1h, acc01, 0, 0, 0);
        acc10 = __builtin_amdgcn_mfma_f32_16x16x32_bf16(a1h, b0h, acc10, 0, 0, 0);
        acc10 = __builtin_amdgcn_mfma_f32_16x16x32_bf16(a1h, b0l, acc10, 0, 0, 0);
        acc10 = __builtin_amdgcn_mfma_f32_16x16x32_bf16(a1l, b0h, acc10, 0, 0, 0);
        acc11 = __builtin_amdgcn_mfma_f32_16x16x32_bf16(a1h, b1h, acc11, 0, 0, 0);
        acc11 = __builtin_amdgcn_mfma_f32_16x16x32_bf16(a1h, b1l, acc11, 0, 0, 0);
        acc11 = __builtin_amdgcn_mfma_f32_16x16x32_bf16(a1l, b1h, acc11, 0, 0, 0);
    }

    // epilogue: D mapping col=lane&15, row=(lane>>4)*4+j
    int orow = row0 + wr*32 + (lane >> 4)*4;
    int ocol = n0 + wc*32 + fr;
    float bc0 = bias[ocol];
    float bc1 = bias[ocol + 16];
#pragma unroll
    for (int j = 0; j < 4; ++j) {
        float v00 = acc00[j] + bc0;
        float v01 = acc01[j] + bc1;
        float v10 = acc10[j] + bc0;
        float v11 = acc11[j] + bc1;
        if (RELU) {
            v00 = fmaxf(v00, 0.f); v01 = fmaxf(v01, 0.f);
            v10 = fmaxf(v10, 0.f); v11 = fmaxf(v11, 0.f);
        }
        C[(size_t)(orow + j)*N + ocol]           = v00;
        C[(size_t)(orow + j)*N + ocol + 16]      = v01;
        C[(size_t)(orow + 16 + j)*N + ocol]      = v10;
        C[(size_t)(orow + 16 + j)*N + ocol + 16] = v11;
    }
}

// ---------------- fallback fp32 head (only if ws too small for MFMA path) ----------------
__global__ __launch_bounds__(256) void head_kernel(const float* __restrict__ feat,
                            const float* __restrict__ hw1, const float* __restrict__ hb1,
                            const float* __restrict__ hw2, const float* __restrict__ hb2,
                            const float* __restrict__ hw3, const float* __restrict__ hb3,
                            float* __restrict__ out) {
    __shared__ float smem[16384];
    float* sfeat = smem;
    float* sh1   = smem + 6144;
    int t = threadIdx.x;
    int row0 = blockIdx.x * 32;

    for (int i = t; i < 32*192; i += 256) sfeat[i] = feat[(size_t)row0*192 + i];
    __syncthreads();

    int c4 = t & 127, rh = t >> 7;
    float4 acc2[16];
    {
        float4 b = *reinterpret_cast<const float4*>(&hb2[4*c4]);
#pragma unroll
        for (int i = 0; i < 16; ++i) acc2[i] = b;
    }
    int c1 = t & 63, rg = t >> 6;

    for (int chunk = 0; chunk < 8; ++chunk) {
        int k0 = chunk * 128;
        float acc1a[8], acc1b[8];
        {
            float ba_ = hb1[k0 + c1], bb_ = hb1[k0 + 64 + c1];
#pragma unroll
            for (int i = 0; i < 8; ++i) { acc1a[i] = ba_; acc1b[i] = bb_; }
        }
#pragma unroll 1
        for (int k = 0; k < 192; k += 4) {
            float wA0 = hw1[(size_t)(k+0)*1024 + k0 + c1];
            float wA1 = hw1[(size_t)(k+1)*1024 + k0 + c1];
            float wA2 = hw1[(size_t)(k+2)*1024 + k0 + c1];
            float wA3 = hw1[(size_t)(k+3)*1024 + k0 + c1];
            float wB0 = hw1[(size_t)(k+0)*1024 + k0 + 64 + c1];
            float wB1 = hw1[(size_t)(k+1)*1024 + k0 + 64 + c1];
            float wB2 = hw1[(size_t)(k+2)*1024 + k0 + 64 + c1];
            float wB3 = hw1[(size_t)(k+3)*1024 + k0 + 64 + c1];
#pragma unroll
            for (int i = 0; i < 8; ++i) {
                float4 fv = *reinterpret_cast<const float4*>(&sfeat[(rg + 4*i)*192 + k]);
                acc1a[i] += fv.x*wA0 + fv.y*wA1 + fv.z*wA2 + fv.w*wA3;
                acc1b[i] += fv.x*wB0 + fv.y*wB1 + fv.z*wB2 + fv.w*wB3;
            }
        }
#pragma unroll
        for (int i = 0; i < 8; ++i) {
            sh1[(rg + 4*i)*128 + c1]      = fmaxf(acc1a[i], 0.f);
            sh1[(rg + 4*i)*128 + 64 + c1] = fmaxf(acc1b[i], 0.f);
        }
        __syncthreads();
        float4 wn[4];
#pragma unroll
        for (int q = 0; q < 4; ++q)
            wn[q] = *reinterpret_cast<const float4*>(&hw2[(size_t)(k0 + q)*512 + 4*c4]);
#pragma unroll 1
        for (int k = 0; k < 128; k += 4) {
            float4 wv[4];
#pragma unroll
            for (int q = 0; q < 4; ++q) wv[q] = wn[q];
            if (k + 4 < 128) {
#pragma unroll
                for (int q = 0; q < 4; ++q)
                    wn[q] = *reinterpret_cast<const float4*>(&hw2[(size_t)(k0 + k + 4 + q)*512 + 4*c4]);
            }
#pragma unroll
            for (int i = 0; i < 16; ++i) {
                float4 h4 = *reinterpret_cast<const float4*>(&sh1[(rh + 2*i)*128 + k]);
                acc2[i].x += h4.x*wv[0].x + h4.y*wv[1].x + h4.z*wv[2].x + h4.w*wv[3].x;
                acc2[i].y += h4.x*wv[0].y + h4.y*wv[1].y + h4.z*wv[2].y + h4.w*wv[3].y;
                acc2[i].z += h4.x*wv[0].z + h4.y*wv[1].z + h4.z*wv[2].z + h4.w*wv[3].z;
                acc2[i].w += h4.x*wv[0].w + h4.y*wv[1].w + h4.z*wv[2].w + h4.w*wv[3].w;
            }
        }
        __syncthreads();
    }
#pragma unroll
    for (int i = 0; i < 16; ++i) {
        float4 v;
        v.x = fmaxf(acc2[i].x, 0.f); v.y = fmaxf(acc2[i].y, 0.f);
        v.z = fmaxf(acc2[i].z, 0.f); v.w = fmaxf(acc2[i].w, 0.f);
        *reinterpret_cast<float4*>(&smem[(rh + 2*i)*512 + 4*c4]) = v;
    }
    __syncthreads();
    int c3 = t & 63, rg3 = t >> 6;
    float acc3a[8], acc3b[8];
    {
        float ba_ = hb3[c3], bb_ = hb3[c3 + 64];
#pragma unroll
        for (int i = 0; i < 8; ++i) { acc3a[i] = ba_; acc3b[i] = bb_; }
    }
#pragma unroll 1
    for (int k = 0; k < 512; k += 4) {
        float wA0 = hw3[(size_t)(k+0)*128 + c3];
        float wA1 = hw3[(size_t)(k+1)*128 + c3];
        float wA2 = hw3[(size_t)(k+2)*128 + c3];
        float wA3 = hw3[(size_t)(k+3)*128 + c3];
        float wB0 = hw3[(size_t)(k+0)*128 + c3 + 64];
        float wB1 = hw3[(size_t)(k+1)*128 + c3 + 64];
        float wB2 = hw3[(size_t)(k+2)*128 + c3 + 64];
        float wB3 = hw3[(size_t)(k+3)*128 + c3 + 64];
#pragma unroll
        for (int i = 0; i < 8; ++i) {
            float4 h4 = *reinterpret_cast<const float4*>(&smem[(rg3 + 4*i)*512 + k]);
            acc3a[i] += h4.x*wA0 + h4.y*wA1 + h4.z*wA2 + h4.w*wA3;
            acc3b[i] += h4.x*wB0 + h4.y*wB1 + h4.z*wB2 + h4.w*wB3;
        }
    }
#pragma unroll
    for (int i = 0; i < 8; ++i) {
        out[(size_t)(row0 + rg3 + 4*i)*128 + c3]      = acc3a[i];
        out[(size_t)(row0 + rg3 + 4*i)*128 + c3 + 64] = acc3b[i];
    }
}

extern "C" void kernel_launch(void* const* d_in, const int* in_sizes, int n_in,
                              void* d_out, int out_size, void* d_ws, size_t ws_size,
                              hipStream_t stream) {
    (void)in_sizes; (void)n_in; (void)out_size;
    const float* x   = (const float*)d_in[0];
    const float* pos = (const float*)d_in[1];
    const float* w1a = (const float*)d_in[2];
    const float* b1a = (const float*)d_in[3];
    const float* w1b = (const float*)d_in[4];
    const float* b1b = (const float*)d_in[5];
    const float* w2a = (const float*)d_in[6];
    const float* b2a = (const float*)d_in[7];
    const float* w2b = (const float*)d_in[8];
    const float* b2b = (const float*)d_in[9];
    const float* w3a = (const float*)d_in[10];
    const float* b3a = (const float*)d_in[11];
    const float* w3b = (const float*)d_in[12];
    const float* b3b = (const float*)d_in[13];
    const float* hw1 = (const float*)d_in[14];
    const float* hb1 = (const float*)d_in[15];
    const float* hw2 = (const float*)d_in[16];
    const float* hb2 = (const float*)d_in[17];
    const float* hw3 = (const float*)d_in[18];
    const float* hb3 = (const float*)d_in[19];
    float* out = (float*)d_out;

    float* ws = (float*)d_ws;
    // offsets in 4-byte units
    float* x0   = ws;                                  // 98304
    float* feat = ws + 98304;                          // 3145728
    float* d2b  = ws + 3244032;                        // 16384
    int*   idxb = (int*)(ws + 3260416);                // 491520
    float* G    = ws + 3751936;                        // 1048576
    ushort* w1h = (ushort*)(ws + 4800512);             // 196608 us = 98304 units
    ushort* w1l = (ushort*)(ws + 4898816);
    ushort* w2h = (ushort*)(ws + 4997120);             // 524288 us = 262144 units
    ushort* w2l = (ushort*)(ws + 5259264);
    ushort* w3h = (ushort*)(ws + 5521408);             // 65536 us = 32768 units
    ushort* w3l = (ushort*)(ws + 5554176);
    const size_t base_units = 5586944;

    // choose M-slicing for h1/h2 scratch (deterministic in ws_size)
    int ns = 0;
    {
        const int cands[5] = {1, 2, 4, 8, 16};
        for (int ci = 0; ci < 5; ++ci) {
            int c = cands[ci];
            size_t need = (base_units + (size_t)(NPTS / c) * 1536) * 4;
            if (need <= ws_size) { ns = c; break; }
        }
    }

    concat_kernel<<<NPTS/256, 256, 0, stream>>>(x, pos, x0);

    d2_kernel<6><<<NPTS/256, 256, 0, stream>>>(x0, 6, d2b);
    knn4_kernel<6><<<NPTS/4, 256, 0, stream>>>(x0, 6, d2b, idxb);
    gmat_kernel<6><<<NPTS/64, 256, 0, stream>>>(x0, 6, w1a, G);
    edgeconv2_kernel<6><<<NPTS/4, 256, 0, stream>>>(x0, 6, G, idxb, w1a, b1a, w1b, b1b, feat, 192);

    d2_kernel<64><<<NPTS/256, 256, 0, stream>>>(feat, 192, d2b);
    knn4_kernel<64><<<NPTS/4, 256, 0, stream>>>(feat, 192, d2b, idxb);
    gmat_kernel<64><<<NPTS/64, 256, 0, stream>>>(feat, 192, w2a, G);
    edgeconv2_kernel<64><<<NPTS/4, 256, 0, stream>>>(feat, 192, G, idxb, w2a, b2a, w2b, b2b, feat + 64, 192);

    d2_kernel<64><<<NPTS/256, 256, 0, stream>>>(feat + 64, 192, d2b);
    knn4_kernel<64><<<NPTS/4, 256, 0, stream>>>(feat + 64, 192, d2b, idxb);
    gmat_kernel<64><<<NPTS/64, 256, 0, stream>>>(feat + 64, 192, w3a, G);
    edgeconv2_kernel<64><<<NPTS/4, 256, 0, stream>>>(feat + 64, 192, G, idxb, w3a, b3a, w3b, b3b, feat + 128, 192);

    if (ns > 0) {
        // split head weights into transposed bf16 hi/lo
        wsplit_kernel<<<(192*1024 + 255)/256, 256, 0, stream>>>(hw1, 192, 1024, w1h, w1l, 192*1024);
        wsplit_kernel<<<(1024*512 + 255)/256, 256, 0, stream>>>(hw2, 1024, 512, w2h, w2l, 1024*512);
        wsplit_kernel<<<(512*128 + 255)/256, 256, 0, stream>>>(hw3, 512, 128, w3h, w3l, 512*128);

        int Ms = NPTS / ns;
        float* h1 = ws + base_units;
        float* h2 = h1 + (size_t)Ms * 1024;
        for (int s = 0; s < ns; ++s) {
            const float* As = feat + (size_t)s * Ms * 192;
            float* outs = out + (size_t)s * Ms * 128;
            mlp_gemm_kernel<true ><<<dim3(Ms/64, 1024/64), 256, 0, stream>>>(As, 192, 192, w1h, w1l, hb1, h1, 1024);
            mlp_gemm_kernel<true ><<<dim3(Ms/64,  512/64), 256, 0, stream>>>(h1, 1024, 1024, w2h, w2l, hb2, h2, 512);
            mlp_gemm_kernel<false><<<dim3(Ms/64,  128/64), 256, 0, stream>>>(h2, 512, 512, w3h, w3l, hb3, outs, 128);
        }
    } else {
        head_kernel<<<NPTS/32, 256, 0, stream>>>(feat, hw1, hb1, hw2, hb2, hw3, hb3, out);
    }
}